// Round 7
// baseline (255.990 us; speedup 1.0000x reference)
//
#include <hip/hip_runtime.h>
#include <math.h>

#define NSD 9
#define NPD 2
#define NAD 7
#define NH  256
#define NIN 16   // NSD + NAD
#define LOSCALE 2048.0f
#define LOINV   (1.0f / 2048.0f)

typedef _Float16 half8 __attribute__((ext_vector_type(8)));
typedef float    floatx4 __attribute__((ext_vector_type(4)));

// ---------------------------------------------------------------------------
// Swapped-operand register-resident design (R4 math, R5 loop structure,
// R6 LDS weight staging, R7 vmcnt-ordering fix).
// R6 post-mortem: the kc-loop issued STAGE (8 global_load_lds) BEFORE the 4
// p1 loads; vmcnt is in-order, so consuming p1 forced the stage loads to
// drain at the TOP of each kc iteration -- prefetch depth 0, serial L2
// round-trip per kc. R7: p1 loads are issued FIRST (sched_barrier-pinned),
// so L1 consumption waits vmcnt(8) and the staged slice stays in flight
// across the full L1 + t-loop (~800 cy) until the barrier. Epilogue gets a
// one-ahead p3 register prefetch for the same reason. s_setprio(1) wraps
// the 48-MFMA t-loop (two independent blocks/CU -> scheduler role
// diversity, T5). Math is bit-identical to R5/R6 (absmax 4.88e-4).
//
// Frag algebra (verified R4): C/D layout lane->(D[slot=(l>>4)*4+r][col=l&15]);
// A-frag lane->(A[row=l&15][k=(l>>4)*8+j]); B-frag lane->(B[k=(l>>4)*8+j][n=l&15]).
// With weight cols permuted by colmap(t,s)=32(t>>1)+8(s>>2)+4(t&1)+(s&3),
// layer-t output slots land exactly on the next layer's B-frag k-indices:
// kc = t>>1, j = 4(t&1)+r. Bias b1 folds via K=16->32 pad (inp[16]=1.0).
// ---------------------------------------------------------------------------

__device__ __forceinline__ void stage16(const _Float16* g, _Float16* l)
{
    __builtin_amdgcn_global_load_lds(
        (const __attribute__((address_space(1))) void*)g,
        (__attribute__((address_space(3))) void*)l, 16, 0, 0);
}

// Pack w1(+b1), w2, w3 into A-fragment arrays (hi/lo pairs, 1 KB each frag).
__global__ __launch_bounds__(64) void k_packW(
    const float* __restrict__ w1, const float* __restrict__ b1,
    const float* __restrict__ w2, const float* __restrict__ w3,
    _Float16* __restrict__ p1, _Float16* __restrict__ p2,
    _Float16* __restrict__ p3)
{
    const int bid  = blockIdx.x;
    const int lane = threadIdx.x;
    const int q = lane >> 4, ln = lane & 15;
    half8 hv, lv;
    _Float16* dst;
    if (bid < 16) {
        // L1: A = [w1 ; b1 ; 0] ^T with colmap'd columns. k in [0,32).
        const int t = bid;
        const int c = 32*(t>>1) + 8*(ln>>2) + 4*(t&1) + (ln&3);
#pragma unroll
        for (int j = 0; j < 8; ++j) {
            const int k = 8*q + j;
            const float x = (k < NIN) ? w1[k*NH + c]
                                      : (k == NIN ? b1[c] : 0.0f);
            const _Float16 h = (_Float16)x;
            hv[j] = h; lv[j] = (_Float16)((x - (float)h) * LOSCALE);
        }
        dst = p1 + (size_t)(t*2) * 512;
    } else if (bid < 144) {
        // L2: A = w2^T, colmap'd columns, natural k (h1 cols arrive natural).
        const int idx = bid - 16, t = idx >> 3, kc = idx & 7;
        const int c = 32*(t>>1) + 8*(ln>>2) + 4*(t&1) + (ln&3);
#pragma unroll
        for (int j = 0; j < 8; ++j) {
            const int k = kc*32 + 8*q + j;
            const float x = w2[k*NH + c];
            const _Float16 h = (_Float16)x;
            hv[j] = h; lv[j] = (_Float16)((x - (float)h) * LOSCALE);
        }
        dst = p2 + (size_t)((t*8 + kc)*2) * 512;
    } else {
        // L3: A = w3^T [9 -> 16 pad rows], natural slots (identity map).
        const int kc = bid - 144;
#pragma unroll
        for (int j = 0; j < 8; ++j) {
            const int k = kc*32 + 8*q + j;
            const float x = (ln < NSD) ? w3[k*NSD + ln] : 0.0f;
            const _Float16 h = (_Float16)x;
            hv[j] = h; lv[j] = (_Float16)((x - (float)h) * LOSCALE);
        }
        dst = p3 + (size_t)(kc*2) * 512;
    }
    *(half8*)&dst[lane*8]       = hv;
    *(half8*)&dst[512 + lane*8] = lv;
}

// ---------------------------------------------------------------------------
// Kernel 1: action proposal + candidate generation (unchanged, verified).
// ---------------------------------------------------------------------------
__global__ __launch_bounds__(256) void k_proposal(
    const float* __restrict__ state, const float* __restrict__ proprio,
    const float* __restrict__ noise, const float* __restrict__ pw1,
    const float* __restrict__ pb1, const float* __restrict__ pw2,
    const float* __restrict__ pb2, float* __restrict__ cand, int B)
{
    const int wave = threadIdx.x >> 6;
    const int lane = threadIdx.x & 63;
    const int b = blockIdx.x * 4 + wave;
    if (b >= B) return;

    float x[11];
#pragma unroll
    for (int k = 0; k < 9; ++k) x[k] = state[b * NSD + k];
    x[9]  = proprio[b * NPD + 0];
    x[10] = proprio[b * NPD + 1];

    float hc[4];
#pragma unroll
    for (int i = 0; i < 4; ++i) {
        const int c = lane + 64 * i;
        float acc = pb1[c];
#pragma unroll
        for (int k = 0; k < 11; ++k) acc = fmaf(x[k], pw1[k * NH + c], acc);
        hc[i] = fmaxf(acc, 0.0f);
    }

    float base[7];
#pragma unroll
    for (int j = 0; j < 7; ++j) {
        float p = 0.0f;
#pragma unroll
        for (int i = 0; i < 4; ++i)
            p = fmaf(hc[i], pw2[(lane + 64 * i) * NAD + j], p);
#pragma unroll
        for (int off = 32; off >= 1; off >>= 1) p += __shfl_xor(p, off, 64);
        base[j] = tanhf(p + pb2[j]);
    }

    if (lane < 8 * NAD) {
        const int s = lane / NAD, j = lane % NAD;
        float bj = base[0];
#pragma unroll
        for (int jj = 1; jj < 7; ++jj) if (j == jj) bj = base[jj];
        float v = bj + 0.2f * noise[((size_t)s * B + b) * NAD + j];
        v = fminf(fmaxf(v, -1.0f), 1.0f);
        cand[((size_t)s * B + b) * NAD + j] = v;
    }
}

// ---------------------------------------------------------------------------
// Kernel 2: rollout. 256 threads = 4 waves; each wave owns 16 (s,b) rows.
// Per-kc w2 slice staged in LDS, double-buffered; 8 barrier pairs per step.
// LDS: 64 KB stage + 5 KB inpL + 1 KB b2L ~= 71 KB -> 2 blocks/CU.
// ---------------------------------------------------------------------------
__global__ __launch_bounds__(256, 2) void k_rollout(
    const float* __restrict__ state, const float* __restrict__ target,
    const float* __restrict__ cand,
    const _Float16* __restrict__ p1, const _Float16* __restrict__ p2,
    const _Float16* __restrict__ p3,
    const float* __restrict__ b2, const float* __restrict__ b3,
    const int* __restrict__ hor_ptr, float* __restrict__ cost, int B)
{
    __shared__ _Float16 w2s[2][16 * 1024];  // [buf][t*1024 + (hi 0..511 | lo 512..1023)]
    __shared__ float inpL[4][16][20];
    __shared__ float b2L[NH];

    const int tid  = threadIdx.x;
    const int wv   = tid >> 6;
    const int lane = tid & 63;
    const int q = lane >> 4, ln = lane & 15;
    const int chunk = blockIdx.x * 4 + wv;
    const int p0 = chunk * 16;
    const int s  = p0 / B;
    const int b0 = p0 % B;
    const int horizon = *hor_ptr;

    // Stage w2 slice kc into w2s[buf]: 32 KB = 8 rounds x 256 thr x 16 B.
    // Slice-linear element e = t*1024 + r  <->  global p2 elem (t*8+kc)*1024 + r.
    // Per-lane global src; wave-uniform LDS dst (base + lane*16, linear).
    auto STAGE = [&](int buf, int kc) {
#pragma unroll
        for (int i = 0; i < 8; ++i) {
            const int e = i * 256 + tid;            // 16B-unit index
            const int t = e >> 7;                   // 128 units per t
            const int r = (e & 127) * 8;            // fp16 offset within t
            const _Float16* g = p2 + (size_t)(t * 8 + kc) * 1024 + r;
            _Float16* l = &w2s[buf][(i * 256 + wv * 64) * 8];
            stage16(g, l);
        }
    };

    b2L[tid] = b2[tid];
    if (q == 0) {
        float* row = &inpL[wv][ln][0];
        const int b = b0 + ln;
#pragma unroll
        for (int k = 0; k < NSD; ++k) row[k] = state[b * NSD + k];
#pragma unroll
        for (int j = 0; j < NAD; ++j)
            row[NSD + j] = cand[((size_t)s * B + b) * NAD + j];
        row[16] = 1.0f; row[17] = 0.0f; row[18] = 0.0f; row[19] = 0.0f;
    }
    float tg[3] = {0.0f, 0.0f, 0.0f};
    if (q == 0) {
#pragma unroll
        for (int r = 0; r < 3; ++r) tg[r] = target[(b0 + ln) * 3 + r];
    }
    float b3v[4];
#pragma unroll
    for (int r = 0; r < 4; ++r) {
        const int f = q * 4 + r;
        b3v[r] = (f < NSD) ? b3[f] : 0.0f;
    }
    float costAcc = 0.0f;

    STAGE(0, 0);                                      // prologue: slice 0
    asm volatile("s_waitcnt vmcnt(0)" ::: "memory");
    __syncthreads();   // b2L + initial inpL + staged slice 0
    int cur = 0;

    const floatx4 z4 = {0.0f, 0.0f, 0.0f, 0.0f};

    for (int h = 0; h < horizon; ++h) {
        // ---- inp B-frag: lane (q,ln) holds inp[ln][8q+j] (hi/lo) ----
        const float* row = &inpL[wv][ln][0];
        float4 fa = {0, 0, 0, 0}, fb = {0, 0, 0, 0};
        if (q < 3) fa = *(const float4*)&row[8 * q];
        if (q < 2) fb = *(const float4*)&row[8 * q + 4];
        half8 bh, bl;
        {
            const float vv[8] = {fa.x, fa.y, fa.z, fa.w, fb.x, fb.y, fb.z, fb.w};
#pragma unroll
            for (int j = 0; j < 8; ++j) {
                const _Float16 hh = (_Float16)vv[j];
                bh[j] = hh;
                bl[j] = (_Float16)((vv[j] - (float)hh) * LOSCALE);
            }
        }

        // ---- L2 accumulator banks (persistent across kc; AGPR-eligible) ----
        floatx4 C1[16], C2[16];
#pragma unroll
        for (int t = 0; t < 16; ++t) { C1[t] = z4; C2[t] = z4; }

        // ---- kc-outer: p1 loads FIRST, then stage, then compute ----
        for (int kc = 0; kc < 8; ++kc) {
            const int nkc = (kc < 7) ? kc + 1 : 0;    // kc=7 restages slice 0
            const int t0 = kc * 2;

            // p1 frags for THIS kc, issued before STAGE so their consumption
            // waits vmcnt(8) and leaves the 8 stage loads in flight (R7 fix).
            const half8 a1h0 = *(const half8*)&p1[(size_t)((t0+0)*2)     * 512 + lane*8];
            const half8 a1l0 = *(const half8*)&p1[(size_t)((t0+0)*2 + 1) * 512 + lane*8];
            const half8 a1h1 = *(const half8*)&p1[(size_t)((t0+1)*2)     * 512 + lane*8];
            const half8 a1l1 = *(const half8*)&p1[(size_t)((t0+1)*2 + 1) * 512 + lane*8];
            __builtin_amdgcn_sched_barrier(0);
            STAGE(cur ^ 1, nkc);                      // for next kc / next h
            __builtin_amdgcn_sched_barrier(0);

            half8 h1h, h1l;
            {
                floatx4 c1t = __builtin_amdgcn_mfma_f32_16x16x32_f16(a1h0, bh, z4, 0, 0, 0);
                floatx4 c2t = __builtin_amdgcn_mfma_f32_16x16x32_f16(a1h0, bl, z4, 0, 0, 0);
                c2t = __builtin_amdgcn_mfma_f32_16x16x32_f16(a1l0, bh, c2t, 0, 0, 0);
#pragma unroll
                for (int r = 0; r < 4; ++r) {
                    const float v = fmaxf(fmaf(c2t[r], LOINV, c1t[r]), 0.0f);
                    const _Float16 hh = (_Float16)v;
                    h1h[r] = hh;
                    h1l[r] = (_Float16)((v - (float)hh) * LOSCALE);
                }
                c1t = __builtin_amdgcn_mfma_f32_16x16x32_f16(a1h1, bh, z4, 0, 0, 0);
                c2t = __builtin_amdgcn_mfma_f32_16x16x32_f16(a1h1, bl, z4, 0, 0, 0);
                c2t = __builtin_amdgcn_mfma_f32_16x16x32_f16(a1l1, bh, c2t, 0, 0, 0);
#pragma unroll
                for (int r = 0; r < 4; ++r) {
                    const float v = fmaxf(fmaf(c2t[r], LOINV, c1t[r]), 0.0f);
                    const _Float16 hh = (_Float16)v;
                    h1h[4 + r] = hh;
                    h1l[4 + r] = (_Float16)((v - (float)hh) * LOSCALE);
                }
            }

            __builtin_amdgcn_s_setprio(1);
#pragma unroll
            for (int t = 0; t < 16; ++t) {
                const half8 a2h = *(const half8*)&w2s[cur][t * 1024 + lane * 8];
                const half8 a2l = *(const half8*)&w2s[cur][t * 1024 + 512 + lane * 8];
                C1[t] = __builtin_amdgcn_mfma_f32_16x16x32_f16(a2h, h1h, C1[t], 0, 0, 0);
                C2[t] = __builtin_amdgcn_mfma_f32_16x16x32_f16(a2h, h1l, C2[t], 0, 0, 0);
                C2[t] = __builtin_amdgcn_mfma_f32_16x16x32_f16(a2l, h1h, C2[t], 0, 0, 0);
            }
            __builtin_amdgcn_s_setprio(0);

            __syncthreads();   // implicit vmcnt(0): stages landed during t-loop
            cur ^= 1;
        }

        // ---- epilogue: finish h2 per t, fuse L3; one-ahead p3 prefetch ----
        floatx4 D1 = z4, D2 = z4;
        half8 h2h, h2l;
        half8 c3h = *(const half8*)&p3[lane * 8];          // kc2=0 hi
        half8 c3l = *(const half8*)&p3[512 + lane * 8];    // kc2=0 lo
#pragma unroll
        for (int t = 0; t < 16; ++t) {
            const float4 bb = *(const float4*)&b2L[32*(t>>1) + 8*q + 4*(t&1)];
            const float bbv[4] = {bb.x, bb.y, bb.z, bb.w};
#pragma unroll
            for (int r = 0; r < 4; ++r) {
                const float v = fmaxf(C1[t][r] + LOINV * C2[t][r] + bbv[r], 0.0f);
                const _Float16 hh = (_Float16)v;
                h2h[(t & 1) * 4 + r] = hh;
                h2l[(t & 1) * 4 + r] = (_Float16)((v - (float)hh) * LOSCALE);
            }
            if (t & 1) {
                const int kc2 = t >> 1;
                half8 n3h, n3l;
                if (kc2 < 7) {
                    n3h = *(const half8*)&p3[(size_t)((kc2+1)*2)     * 512 + lane*8];
                    n3l = *(const half8*)&p3[(size_t)((kc2+1)*2 + 1) * 512 + lane*8];
                }
                D1 = __builtin_amdgcn_mfma_f32_16x16x32_f16(c3h, h2h, D1, 0, 0, 0);
                D2 = __builtin_amdgcn_mfma_f32_16x16x32_f16(c3h, h2l, D2, 0, 0, 0);
                D2 = __builtin_amdgcn_mfma_f32_16x16x32_f16(c3l, h2h, D2, 0, 0, 0);
                if (kc2 < 7) { c3h = n3h; c3l = n3l; }
            }
        }
        float v[4];
#pragma unroll
        for (int r = 0; r < 4; ++r)
            v[r] = D1[r] + LOINV * D2[r] + b3v[r];

        // lane (q,ln) holds sim'[ln][features 4q..4q+3]
        if (q == 0) {
            const float d0 = v[0] - tg[0], d1 = v[1] - tg[1], d2 = v[2] - tg[2];
            costAcc += d0 * d0 + d1 * d1 + d2 * d2;
        }
        if (q < 2) {
            const float4 w4 = {v[0], v[1], v[2], v[3]};
            *(float4*)&inpL[wv][ln][4 * q] = w4;
        } else if (q == 2) {
            inpL[wv][ln][8] = v[0];   // feature 8 only (9..11 would hit cand)
        }
        // order sim' writes before next iteration's cross-lane reads
        asm volatile("s_waitcnt lgkmcnt(0)" ::: "memory");
    }

    if (q == 0) cost[(size_t)s * B + b0 + ln] = costAcc;
}

// ---------------------------------------------------------------------------
// Kernel 3: first-argmin over samples + gather best action (unchanged).
// ---------------------------------------------------------------------------
__global__ __launch_bounds__(256) void k_select(
    const float* __restrict__ cost, const float* __restrict__ cand,
    float* __restrict__ out, int B, int S)
{
    const int b = blockIdx.x * 256 + threadIdx.x;
    if (b >= B) return;
    float best = cost[b];
    int bs = 0;
    for (int s = 1; s < S; ++s) {
        const float c = cost[(size_t)s * B + b];
        if (c < best) { best = c; bs = s; }
    }
#pragma unroll
    for (int j = 0; j < NAD; ++j)
        out[b * NAD + j] = cand[((size_t)bs * B + b) * NAD + j];
}

// ---------------------------------------------------------------------------
extern "C" void kernel_launch(void* const* d_in, const int* in_sizes, int n_in,
                              void* d_out, int out_size, void* d_ws, size_t ws_size,
                              hipStream_t stream)
{
    const float* state   = (const float*)d_in[0];
    const float* proprio = (const float*)d_in[1];
    const float* target  = (const float*)d_in[2];
    const float* noise   = (const float*)d_in[3];
    const float* pw1     = (const float*)d_in[4];
    const float* pb1     = (const float*)d_in[5];
    const float* pw2     = (const float*)d_in[6];
    const float* pb2     = (const float*)d_in[7];
    const float* w1      = (const float*)d_in[8];
    const float* b1      = (const float*)d_in[9];
    const float* w2      = (const float*)d_in[10];
    const float* b2      = (const float*)d_in[11];
    const float* w3      = (const float*)d_in[12];
    const float* b3      = (const float*)d_in[13];
    const int*   horizon = (const int*)d_in[14];

    const int B = in_sizes[0] / NSD;             // 8192
    const int S = in_sizes[3] / (B * NAD);       // 8

    float* cand = (float*)d_ws;                            // S*B*7 floats
    float* cost = cand + (size_t)S * B * NAD;              // S*B floats
    _Float16* p1 = (_Float16*)(cost + (size_t)S * B);      // 16*2*512 fp16
    _Float16* p2 = p1 + 16 * 2 * 512;                      // 128*2*512 fp16
    _Float16* p3 = p2 + 128 * 2 * 512;                     // 8*2*512 fp16
    float* out  = (float*)d_out;

    k_packW<<<dim3(152), dim3(64), 0, stream>>>(w1, b1, w2, w3, p1, p2, p3);
    k_proposal<<<dim3((B + 3) / 4), dim3(256), 0, stream>>>(
        state, proprio, noise, pw1, pb1, pw2, pb2, cand, B);
    k_rollout<<<dim3((S * B) / 64), dim3(256), 0, stream>>>(
        state, target, cand, p1, p2, p3, b2, b3, horizon, cost, B);
    k_select<<<dim3((B + 255) / 256), dim3(256), 0, stream>>>(
        cost, cand, out, B, S);
}

// Round 8
// 238.095 us; speedup vs baseline: 1.0752x; 1.0752x over previous
//
#include <hip/hip_runtime.h>
#include <math.h>

#define NSD 9
#define NPD 2
#define NAD 7
#define NH  256
#define NIN 16   // NSD + NAD
#define LOSCALE 2048.0f
#define LOINV   (1.0f / 2048.0f)

typedef _Float16 half8 __attribute__((ext_vector_type(8)));
typedef float    floatx4 __attribute__((ext_vector_type(4)));

// ---------------------------------------------------------------------------
// Swapped-operand register-resident design (R4 math, R5 loop structure,
// R6 LDS weight staging, R8 vmcnt decoupling).
// R7 post-mortem: holding p1 prefetch in VGPRs across STAGE spilled (arch
// budget for 2 waves/SIMD is 128 incl. nothing spare; WRITE_SIZE 50 MB).
// R8: the per-kc p1 slice (4 KB) is staged INTO LDS alongside the w2 slice
// (36 KB total, 9 global_load_lds rounds). The kc loop now contains NO
// VGPR global loads: L1 reads p1 frags via ds_read (lgkmcnt), so consuming
// them does not drain the in-flight stage loads (vmcnt is in-order).
// Every STAGE has the full L1 + t-loop (~800 cy) before the barrier drain.
// Zero extra register pressure vs R6. Math bit-identical (absmax 4.88e-4).
//
// Frag algebra (verified R4): C/D layout lane->(D[slot=(l>>4)*4+r][col=l&15]);
// A-frag lane->(A[row=l&15][k=(l>>4)*8+j]); B-frag lane->(B[k=(l>>4)*8+j][n=l&15]).
// With weight cols permuted by colmap(t,s)=32(t>>1)+8(s>>2)+4(t&1)+(s&3),
// layer-t output slots land exactly on the next layer's B-frag k-indices:
// kc = t>>1, j = 4(t&1)+r. Bias b1 folds via K=16->32 pad (inp[16]=1.0).
// ---------------------------------------------------------------------------

__device__ __forceinline__ void stage16(const _Float16* g, _Float16* l)
{
    __builtin_amdgcn_global_load_lds(
        (const __attribute__((address_space(1))) void*)g,
        (__attribute__((address_space(3))) void*)l, 16, 0, 0);
}

// Pack w1(+b1), w2, w3 into A-fragment arrays (hi/lo pairs, 1 KB each frag).
__global__ __launch_bounds__(64) void k_packW(
    const float* __restrict__ w1, const float* __restrict__ b1,
    const float* __restrict__ w2, const float* __restrict__ w3,
    _Float16* __restrict__ p1, _Float16* __restrict__ p2,
    _Float16* __restrict__ p3)
{
    const int bid  = blockIdx.x;
    const int lane = threadIdx.x;
    const int q = lane >> 4, ln = lane & 15;
    half8 hv, lv;
    _Float16* dst;
    if (bid < 16) {
        // L1: A = [w1 ; b1 ; 0] ^T with colmap'd columns. k in [0,32).
        const int t = bid;
        const int c = 32*(t>>1) + 8*(ln>>2) + 4*(t&1) + (ln&3);
#pragma unroll
        for (int j = 0; j < 8; ++j) {
            const int k = 8*q + j;
            const float x = (k < NIN) ? w1[k*NH + c]
                                      : (k == NIN ? b1[c] : 0.0f);
            const _Float16 h = (_Float16)x;
            hv[j] = h; lv[j] = (_Float16)((x - (float)h) * LOSCALE);
        }
        dst = p1 + (size_t)(t*2) * 512;
    } else if (bid < 144) {
        // L2: A = w2^T, colmap'd columns, natural k (h1 cols arrive natural).
        const int idx = bid - 16, t = idx >> 3, kc = idx & 7;
        const int c = 32*(t>>1) + 8*(ln>>2) + 4*(t&1) + (ln&3);
#pragma unroll
        for (int j = 0; j < 8; ++j) {
            const int k = kc*32 + 8*q + j;
            const float x = w2[k*NH + c];
            const _Float16 h = (_Float16)x;
            hv[j] = h; lv[j] = (_Float16)((x - (float)h) * LOSCALE);
        }
        dst = p2 + (size_t)((t*8 + kc)*2) * 512;
    } else {
        // L3: A = w3^T [9 -> 16 pad rows], natural slots (identity map).
        const int kc = bid - 144;
#pragma unroll
        for (int j = 0; j < 8; ++j) {
            const int k = kc*32 + 8*q + j;
            const float x = (ln < NSD) ? w3[k*NSD + ln] : 0.0f;
            const _Float16 h = (_Float16)x;
            hv[j] = h; lv[j] = (_Float16)((x - (float)h) * LOSCALE);
        }
        dst = p3 + (size_t)(kc*2) * 512;
    }
    *(half8*)&dst[lane*8]       = hv;
    *(half8*)&dst[512 + lane*8] = lv;
}

// ---------------------------------------------------------------------------
// Kernel 1: action proposal + candidate generation (unchanged, verified).
// ---------------------------------------------------------------------------
__global__ __launch_bounds__(256) void k_proposal(
    const float* __restrict__ state, const float* __restrict__ proprio,
    const float* __restrict__ noise, const float* __restrict__ pw1,
    const float* __restrict__ pb1, const float* __restrict__ pw2,
    const float* __restrict__ pb2, float* __restrict__ cand, int B)
{
    const int wave = threadIdx.x >> 6;
    const int lane = threadIdx.x & 63;
    const int b = blockIdx.x * 4 + wave;
    if (b >= B) return;

    float x[11];
#pragma unroll
    for (int k = 0; k < 9; ++k) x[k] = state[b * NSD + k];
    x[9]  = proprio[b * NPD + 0];
    x[10] = proprio[b * NPD + 1];

    float hc[4];
#pragma unroll
    for (int i = 0; i < 4; ++i) {
        const int c = lane + 64 * i;
        float acc = pb1[c];
#pragma unroll
        for (int k = 0; k < 11; ++k) acc = fmaf(x[k], pw1[k * NH + c], acc);
        hc[i] = fmaxf(acc, 0.0f);
    }

    float base[7];
#pragma unroll
    for (int j = 0; j < 7; ++j) {
        float p = 0.0f;
#pragma unroll
        for (int i = 0; i < 4; ++i)
            p = fmaf(hc[i], pw2[(lane + 64 * i) * NAD + j], p);
#pragma unroll
        for (int off = 32; off >= 1; off >>= 1) p += __shfl_xor(p, off, 64);
        base[j] = tanhf(p + pb2[j]);
    }

    if (lane < 8 * NAD) {
        const int s = lane / NAD, j = lane % NAD;
        float bj = base[0];
#pragma unroll
        for (int jj = 1; jj < 7; ++jj) if (j == jj) bj = base[jj];
        float v = bj + 0.2f * noise[((size_t)s * B + b) * NAD + j];
        v = fminf(fmaxf(v, -1.0f), 1.0f);
        cand[((size_t)s * B + b) * NAD + j] = v;
    }
}

// ---------------------------------------------------------------------------
// Kernel 2: rollout. 256 threads = 4 waves; each wave owns 16 (s,b) rows.
// Per-kc {w2 slice 32 KB + p1 slice 4 KB} staged in LDS, double-buffered;
// one barrier per kc. LDS: 72 KB stage + 5 KB inpL + 1 KB b2L = 78 KB
// -> 2 blocks/CU. No VGPR global loads in the kc loop (vmcnt decoupled).
// ---------------------------------------------------------------------------
__global__ __launch_bounds__(256, 2) void k_rollout(
    const float* __restrict__ state, const float* __restrict__ target,
    const float* __restrict__ cand,
    const _Float16* __restrict__ p1, const _Float16* __restrict__ p2,
    const _Float16* __restrict__ p3,
    const float* __restrict__ b2, const float* __restrict__ b3,
    const int* __restrict__ hor_ptr, float* __restrict__ cost, int B)
{
    // [buf][ w2: t*1024 + (hi 0..511 | lo 512..1023), t=0..15  (fp16 units)
    //        p1: 16384 + tt*1024 + (hi | lo), tt=0..1 ]
    __shared__ _Float16 sb[2][18432];
    __shared__ float inpL[4][16][20];
    __shared__ float b2L[NH];

    const int tid  = threadIdx.x;
    const int wv   = tid >> 6;
    const int lane = tid & 63;
    const int q = lane >> 4, ln = lane & 15;
    const int chunk = blockIdx.x * 4 + wv;
    const int p0 = chunk * 16;
    const int s  = p0 / B;
    const int b0 = p0 % B;
    const int horizon = *hor_ptr;

    // Stage {w2 slice kc (32 KB) + p1 slice kc (4 KB)} into sb[buf]:
    // 36 KB = 9 rounds x 256 thr x 16 B. Per-lane global src (linear in
    // lane within each wave's 64-unit range; region boundary at unit 2048
    // is 64-aligned so the branch is wave-uniform); wave-uniform LDS dst.
    auto STAGE = [&](int buf, int kc) {
#pragma unroll
        for (int i = 0; i < 9; ++i) {
            const int u = i * 256 + tid;            // 16B-unit index, 0..2303
            const _Float16* g;
            if (u < 2048) {                          // w2 region
                const int t = u >> 7;                // 128 units per t
                const int r = (u & 127) * 8;         // fp16 offset within t
                g = p2 + (size_t)(t * 8 + kc) * 1024 + r;
            } else {                                 // p1 region
                const int v = u - 2048;
                const int tt = v >> 7;
                const int r = (v & 127) * 8;
                g = p1 + (size_t)(kc * 2 + tt) * 1024 + r;
            }
            _Float16* l = &sb[buf][(size_t)(i * 256 + wv * 64) * 8];
            stage16(g, l);
        }
    };

    b2L[tid] = b2[tid];
    if (q == 0) {
        float* row = &inpL[wv][ln][0];
        const int b = b0 + ln;
#pragma unroll
        for (int k = 0; k < NSD; ++k) row[k] = state[b * NSD + k];
#pragma unroll
        for (int j = 0; j < NAD; ++j)
            row[NSD + j] = cand[((size_t)s * B + b) * NAD + j];
        row[16] = 1.0f; row[17] = 0.0f; row[18] = 0.0f; row[19] = 0.0f;
    }
    float tg[3] = {0.0f, 0.0f, 0.0f};
    if (q == 0) {
#pragma unroll
        for (int r = 0; r < 3; ++r) tg[r] = target[(b0 + ln) * 3 + r];
    }
    float b3v[4];
#pragma unroll
    for (int r = 0; r < 4; ++r) {
        const int f = q * 4 + r;
        b3v[r] = (f < NSD) ? b3[f] : 0.0f;
    }
    float costAcc = 0.0f;

    STAGE(0, 0);                                      // prologue: slice 0
    asm volatile("s_waitcnt vmcnt(0)" ::: "memory");
    __syncthreads();   // b2L + initial inpL + staged slice 0
    int cur = 0;

    const floatx4 z4 = {0.0f, 0.0f, 0.0f, 0.0f};

    for (int h = 0; h < horizon; ++h) {
        // ---- inp B-frag: lane (q,ln) holds inp[ln][8q+j] (hi/lo) ----
        const float* row = &inpL[wv][ln][0];
        float4 fa = {0, 0, 0, 0}, fb = {0, 0, 0, 0};
        if (q < 3) fa = *(const float4*)&row[8 * q];
        if (q < 2) fb = *(const float4*)&row[8 * q + 4];
        half8 bh, bl;
        {
            const float vv[8] = {fa.x, fa.y, fa.z, fa.w, fb.x, fb.y, fb.z, fb.w};
#pragma unroll
            for (int j = 0; j < 8; ++j) {
                const _Float16 hh = (_Float16)vv[j];
                bh[j] = hh;
                bl[j] = (_Float16)((vv[j] - (float)hh) * LOSCALE);
            }
        }

        // ---- L2 accumulator banks (persistent across kc; AGPR-eligible) ----
        floatx4 C1[16], C2[16];
#pragma unroll
        for (int t = 0; t < 16; ++t) { C1[t] = z4; C2[t] = z4; }

        // ---- kc loop: stage next slice; L1 + t-loop all from LDS ----
        for (int kc = 0; kc < 8; ++kc) {
            const int nkc = (kc < 7) ? kc + 1 : 0;    // kc=7 restages slice 0
            STAGE(cur ^ 1, nkc);                      // for next kc / next h

            // L1 for this kc from sb[cur].p1 (ds_read -> lgkmcnt only).
            half8 h1h, h1l;
            {
                const half8 a1h0 = *(const half8*)&sb[cur][16384 + lane*8];
                const half8 a1l0 = *(const half8*)&sb[cur][16384 + 512 + lane*8];
                const half8 a1h1 = *(const half8*)&sb[cur][16384 + 1024 + lane*8];
                const half8 a1l1 = *(const half8*)&sb[cur][16384 + 1536 + lane*8];
                floatx4 c1t = __builtin_amdgcn_mfma_f32_16x16x32_f16(a1h0, bh, z4, 0, 0, 0);
                floatx4 c2t = __builtin_amdgcn_mfma_f32_16x16x32_f16(a1h0, bl, z4, 0, 0, 0);
                c2t = __builtin_amdgcn_mfma_f32_16x16x32_f16(a1l0, bh, c2t, 0, 0, 0);
#pragma unroll
                for (int r = 0; r < 4; ++r) {
                    const float v = fmaxf(fmaf(c2t[r], LOINV, c1t[r]), 0.0f);
                    const _Float16 hh = (_Float16)v;
                    h1h[r] = hh;
                    h1l[r] = (_Float16)((v - (float)hh) * LOSCALE);
                }
                c1t = __builtin_amdgcn_mfma_f32_16x16x32_f16(a1h1, bh, z4, 0, 0, 0);
                c2t = __builtin_amdgcn_mfma_f32_16x16x32_f16(a1h1, bl, z4, 0, 0, 0);
                c2t = __builtin_amdgcn_mfma_f32_16x16x32_f16(a1l1, bh, c2t, 0, 0, 0);
#pragma unroll
                for (int r = 0; r < 4; ++r) {
                    const float v = fmaxf(fmaf(c2t[r], LOINV, c1t[r]), 0.0f);
                    const _Float16 hh = (_Float16)v;
                    h1h[4 + r] = hh;
                    h1l[4 + r] = (_Float16)((v - (float)hh) * LOSCALE);
                }
            }

            // t-loop: 16 t x 3 MFMA on sb[cur].w2.
#pragma unroll
            for (int t = 0; t < 16; ++t) {
                const half8 a2h = *(const half8*)&sb[cur][t * 1024 + lane * 8];
                const half8 a2l = *(const half8*)&sb[cur][t * 1024 + 512 + lane * 8];
                C1[t] = __builtin_amdgcn_mfma_f32_16x16x32_f16(a2h, h1h, C1[t], 0, 0, 0);
                C2[t] = __builtin_amdgcn_mfma_f32_16x16x32_f16(a2h, h1l, C2[t], 0, 0, 0);
                C2[t] = __builtin_amdgcn_mfma_f32_16x16x32_f16(a2l, h1h, C2[t], 0, 0, 0);
            }

            __syncthreads();   // implicit vmcnt(0): stage landed during L1+t-loop
            cur ^= 1;
        }

        // ---- epilogue: finish h2 per t, fuse L3 per completed k-slice ----
        floatx4 D1 = z4, D2 = z4;
        half8 h2h, h2l;
#pragma unroll
        for (int t = 0; t < 16; ++t) {
            const float4 bb = *(const float4*)&b2L[32*(t>>1) + 8*q + 4*(t&1)];
            const float bbv[4] = {bb.x, bb.y, bb.z, bb.w};
#pragma unroll
            for (int r = 0; r < 4; ++r) {
                const float v = fmaxf(C1[t][r] + LOINV * C2[t][r] + bbv[r], 0.0f);
                const _Float16 hh = (_Float16)v;
                h2h[(t & 1) * 4 + r] = hh;
                h2l[(t & 1) * 4 + r] = (_Float16)((v - (float)hh) * LOSCALE);
            }
            if (t & 1) {
                const int kc2 = t >> 1;
                const half8 a3h = *(const half8*)&p3[(size_t)(kc2*2)     * 512 + lane*8];
                const half8 a3l = *(const half8*)&p3[(size_t)(kc2*2 + 1) * 512 + lane*8];
                D1 = __builtin_amdgcn_mfma_f32_16x16x32_f16(a3h, h2h, D1, 0, 0, 0);
                D2 = __builtin_amdgcn_mfma_f32_16x16x32_f16(a3h, h2l, D2, 0, 0, 0);
                D2 = __builtin_amdgcn_mfma_f32_16x16x32_f16(a3l, h2h, D2, 0, 0, 0);
            }
        }
        float v[4];
#pragma unroll
        for (int r = 0; r < 4; ++r)
            v[r] = D1[r] + LOINV * D2[r] + b3v[r];

        // lane (q,ln) holds sim'[ln][features 4q..4q+3]
        if (q == 0) {
            const float d0 = v[0] - tg[0], d1 = v[1] - tg[1], d2 = v[2] - tg[2];
            costAcc += d0 * d0 + d1 * d1 + d2 * d2;
        }
        if (q < 2) {
            const float4 w4 = {v[0], v[1], v[2], v[3]};
            *(float4*)&inpL[wv][ln][4 * q] = w4;
        } else if (q == 2) {
            inpL[wv][ln][8] = v[0];   // feature 8 only (9..11 would hit cand)
        }
        // order sim' writes before next iteration's cross-lane reads
        asm volatile("s_waitcnt lgkmcnt(0)" ::: "memory");
    }

    if (q == 0) cost[(size_t)s * B + b0 + ln] = costAcc;
}

// ---------------------------------------------------------------------------
// Kernel 3: first-argmin over samples + gather best action (unchanged).
// ---------------------------------------------------------------------------
__global__ __launch_bounds__(256) void k_select(
    const float* __restrict__ cost, const float* __restrict__ cand,
    float* __restrict__ out, int B, int S)
{
    const int b = blockIdx.x * 256 + threadIdx.x;
    if (b >= B) return;
    float best = cost[b];
    int bs = 0;
    for (int s = 1; s < S; ++s) {
        const float c = cost[(size_t)s * B + b];
        if (c < best) { best = c; bs = s; }
    }
#pragma unroll
    for (int j = 0; j < NAD; ++j)
        out[b * NAD + j] = cand[((size_t)bs * B + b) * NAD + j];
}

// ---------------------------------------------------------------------------
extern "C" void kernel_launch(void* const* d_in, const int* in_sizes, int n_in,
                              void* d_out, int out_size, void* d_ws, size_t ws_size,
                              hipStream_t stream)
{
    const float* state   = (const float*)d_in[0];
    const float* proprio = (const float*)d_in[1];
    const float* target  = (const float*)d_in[2];
    const float* noise   = (const float*)d_in[3];
    const float* pw1     = (const float*)d_in[4];
    const float* pb1     = (const float*)d_in[5];
    const float* pw2     = (const float*)d_in[6];
    const float* pb2     = (const float*)d_in[7];
    const float* w1      = (const float*)d_in[8];
    const float* b1      = (const float*)d_in[9];
    const float* w2      = (const float*)d_in[10];
    const float* b2      = (const float*)d_in[11];
    const float* w3      = (const float*)d_in[12];
    const float* b3      = (const float*)d_in[13];
    const int*   horizon = (const int*)d_in[14];

    const int B = in_sizes[0] / NSD;             // 8192
    const int S = in_sizes[3] / (B * NAD);       // 8

    float* cand = (float*)d_ws;                            // S*B*7 floats
    float* cost = cand + (size_t)S * B * NAD;              // S*B floats
    _Float16* p1 = (_Float16*)(cost + (size_t)S * B);      // 16*2*512 fp16
    _Float16* p2 = p1 + 16 * 2 * 512;                      // 128*2*512 fp16
    _Float16* p3 = p2 + 128 * 2 * 512;                     // 8*2*512 fp16
    float* out  = (float*)d_out;

    k_packW<<<dim3(152), dim3(64), 0, stream>>>(w1, b1, w2, w3, p1, p2, p3);
    k_proposal<<<dim3((B + 3) / 4), dim3(256), 0, stream>>>(
        state, proprio, noise, pw1, pb1, pw2, pb2, cand, B);
    k_rollout<<<dim3((S * B) / 64), dim3(256), 0, stream>>>(
        state, target, cand, p1, p2, p3, b2, b3, horizon, cost, B);
    k_select<<<dim3((B + 255) / 256), dim3(256), 0, stream>>>(
        cost, cand, out, B, S);
}

// Round 9
// 221.678 us; speedup vs baseline: 1.1548x; 1.0741x over previous
//
#include <hip/hip_runtime.h>
#include <math.h>

#define NSD 9
#define NPD 2
#define NAD 7
#define NH  256
#define NIN 16   // NSD + NAD
#define LOSCALE 2048.0f
#define LOINV   (1.0f / 2048.0f)

typedef _Float16 half8 __attribute__((ext_vector_type(8)));
typedef float    floatx4 __attribute__((ext_vector_type(4)));

// ---------------------------------------------------------------------------
// Swapped-operand register-resident design (R4 math, R5 loop structure,
// R6 LDS weight staging, R8 vmcnt decoupling, R9 contiguous-slice staging).
// Budget equation (R8 post-mortem): 2 waves/SIMD -> arch VGPR + AGPR <= 256;
// C1/C2 accumulators = 128 AGPR -> arch cap 128. R8's branchy STAGE address
// math (9 unrolled {shift/mask/mul} address computations) blew the cap ->
// 41 MB scratch. R9: weights are repacked so each kc-slice {16 w2 frag
// pairs + 2 p1 frag pairs} is ONE contiguous 36 KB global block whose
// internal layout equals the LDS layout. STAGE = one base pointer + nine
// constant-stride global_load_lds. No branch, no muls, ~2 live VGPRs.
// kc loop still has NO VGPR global loads (p1 read from LDS via lgkmcnt),
// so staged loads stay in flight across L1 + t-loop until the barrier.
// Math bit-identical to R5-R8 (absmax 4.88e-4).
//
// Frag algebra (verified R4): C/D layout lane->(D[slot=(l>>4)*4+r][col=l&15]);
// A-frag lane->(A[row=l&15][k=(l>>4)*8+j]); B-frag lane->(B[k=(l>>4)*8+j][n=l&15]).
// With weight cols permuted by colmap(t,s)=32(t>>1)+8(s>>2)+4(t&1)+(s&3),
// layer-t output slots land exactly on the next layer's B-frag k-indices:
// kc = t>>1, j = 4(t&1)+r. Bias b1 folds via K=16->32 pad (inp[16]=1.0).
//
// pc layout, slice kc (18432 fp16 units = 36 KB):
//   units     0..16383 : w2 frags, t*1024 + (hi 0..511 | lo 512..1023)
//   units 16384..18431 : p1 frags, tt*1024 + (hi | lo), t = kc*2 + tt
// ---------------------------------------------------------------------------

__device__ __forceinline__ void stage16(const _Float16* g, _Float16* l)
{
    __builtin_amdgcn_global_load_lds(
        (const __attribute__((address_space(1))) void*)g,
        (__attribute__((address_space(3))) void*)l, 16, 0, 0);
}

// Pack w1(+b1)+w2 into the combined slice buffer pc, w3 into p3.
__global__ __launch_bounds__(64) void k_packW(
    const float* __restrict__ w1, const float* __restrict__ b1,
    const float* __restrict__ w2, const float* __restrict__ w3,
    _Float16* __restrict__ pc, _Float16* __restrict__ p3)
{
    const int bid  = blockIdx.x;
    const int lane = threadIdx.x;
    const int q = lane >> 4, ln = lane & 15;
    half8 hv, lv;
    _Float16* dst;
    if (bid < 16) {
        // L1: A = [w1 ; b1 ; 0] ^T with colmap'd columns. k in [0,32).
        const int t = bid;
        const int c = 32*(t>>1) + 8*(ln>>2) + 4*(t&1) + (ln&3);
#pragma unroll
        for (int j = 0; j < 8; ++j) {
            const int k = 8*q + j;
            const float x = (k < NIN) ? w1[k*NH + c]
                                      : (k == NIN ? b1[c] : 0.0f);
            const _Float16 h = (_Float16)x;
            hv[j] = h; lv[j] = (_Float16)((x - (float)h) * LOSCALE);
        }
        dst = pc + (size_t)(t >> 1) * 18432 + 16384 + (size_t)(t & 1) * 1024;
    } else if (bid < 144) {
        // L2: A = w2^T, colmap'd columns, natural k (h1 cols arrive natural).
        const int idx = bid - 16, t = idx >> 3, kc = idx & 7;
        const int c = 32*(t>>1) + 8*(ln>>2) + 4*(t&1) + (ln&3);
#pragma unroll
        for (int j = 0; j < 8; ++j) {
            const int k = kc*32 + 8*q + j;
            const float x = w2[k*NH + c];
            const _Float16 h = (_Float16)x;
            hv[j] = h; lv[j] = (_Float16)((x - (float)h) * LOSCALE);
        }
        dst = pc + (size_t)kc * 18432 + (size_t)t * 1024;
    } else {
        // L3: A = w3^T [9 -> 16 pad rows], natural slots (identity map).
        const int kc = bid - 144;
#pragma unroll
        for (int j = 0; j < 8; ++j) {
            const int k = kc*32 + 8*q + j;
            const float x = (ln < NSD) ? w3[k*NSD + ln] : 0.0f;
            const _Float16 h = (_Float16)x;
            hv[j] = h; lv[j] = (_Float16)((x - (float)h) * LOSCALE);
        }
        dst = p3 + (size_t)kc * 1024;
    }
    *(half8*)&dst[lane*8]       = hv;
    *(half8*)&dst[512 + lane*8] = lv;
}

// ---------------------------------------------------------------------------
// Kernel 1: action proposal + candidate generation (unchanged, verified).
// ---------------------------------------------------------------------------
__global__ __launch_bounds__(256) void k_proposal(
    const float* __restrict__ state, const float* __restrict__ proprio,
    const float* __restrict__ noise, const float* __restrict__ pw1,
    const float* __restrict__ pb1, const float* __restrict__ pw2,
    const float* __restrict__ pb2, float* __restrict__ cand, int B)
{
    const int wave = threadIdx.x >> 6;
    const int lane = threadIdx.x & 63;
    const int b = blockIdx.x * 4 + wave;
    if (b >= B) return;

    float x[11];
#pragma unroll
    for (int k = 0; k < 9; ++k) x[k] = state[b * NSD + k];
    x[9]  = proprio[b * NPD + 0];
    x[10] = proprio[b * NPD + 1];

    float hc[4];
#pragma unroll
    for (int i = 0; i < 4; ++i) {
        const int c = lane + 64 * i;
        float acc = pb1[c];
#pragma unroll
        for (int k = 0; k < 11; ++k) acc = fmaf(x[k], pw1[k * NH + c], acc);
        hc[i] = fmaxf(acc, 0.0f);
    }

    float base[7];
#pragma unroll
    for (int j = 0; j < 7; ++j) {
        float p = 0.0f;
#pragma unroll
        for (int i = 0; i < 4; ++i)
            p = fmaf(hc[i], pw2[(lane + 64 * i) * NAD + j], p);
#pragma unroll
        for (int off = 32; off >= 1; off >>= 1) p += __shfl_xor(p, off, 64);
        base[j] = tanhf(p + pb2[j]);
    }

    if (lane < 8 * NAD) {
        const int s = lane / NAD, j = lane % NAD;
        float bj = base[0];
#pragma unroll
        for (int jj = 1; jj < 7; ++jj) if (j == jj) bj = base[jj];
        float v = bj + 0.2f * noise[((size_t)s * B + b) * NAD + j];
        v = fminf(fmaxf(v, -1.0f), 1.0f);
        cand[((size_t)s * B + b) * NAD + j] = v;
    }
}

// ---------------------------------------------------------------------------
// Kernel 2: rollout. 256 threads = 4 waves; each wave owns 16 (s,b) rows.
// Per-kc 36 KB slice staged in LDS (contiguous src), double-buffered; one
// barrier per kc. LDS: 72 KB stage + 5 KB inpL + 1 KB b2L ~= 78 KB
// -> 2 blocks/CU. No VGPR global loads in the kc loop.
// ---------------------------------------------------------------------------
__global__ __launch_bounds__(256, 2) void k_rollout(
    const float* __restrict__ state, const float* __restrict__ target,
    const float* __restrict__ cand,
    const _Float16* __restrict__ pc, const _Float16* __restrict__ p3,
    const float* __restrict__ b2, const float* __restrict__ b3,
    const int* __restrict__ hor_ptr, float* __restrict__ cost, int B)
{
    __shared__ _Float16 sb[2][18432];   // slice layout == pc slice layout
    __shared__ float inpL[4][16][20];
    __shared__ float b2L[NH];

    const int tid  = threadIdx.x;
    const int wv   = tid >> 6;
    const int lane = tid & 63;
    const int q = lane >> 4, ln = lane & 15;
    const int chunk = blockIdx.x * 4 + wv;
    const int p0 = chunk * 16;
    const int s  = p0 / B;
    const int b0 = p0 % B;
    const int horizon = *hor_ptr;

    // Stage slice kc: 9 rounds x 256 thr x 16 B, contiguous global src.
    auto STAGE = [&](int buf, int kc) {
        const _Float16* gbase = pc + (size_t)kc * 18432 + tid * 8;
        _Float16* lbase = &sb[buf][wv * 512];
#pragma unroll
        for (int i = 0; i < 9; ++i)
            stage16(gbase + i * 2048, lbase + i * 2048);
    };

    b2L[tid] = b2[tid];
    if (q == 0) {
        float* row = &inpL[wv][ln][0];
        const int b = b0 + ln;
#pragma unroll
        for (int k = 0; k < NSD; ++k) row[k] = state[b * NSD + k];
#pragma unroll
        for (int j = 0; j < NAD; ++j)
            row[NSD + j] = cand[((size_t)s * B + b) * NAD + j];
        row[16] = 1.0f; row[17] = 0.0f; row[18] = 0.0f; row[19] = 0.0f;
    }
    float tg[3] = {0.0f, 0.0f, 0.0f};
    if (q == 0) {
#pragma unroll
        for (int r = 0; r < 3; ++r) tg[r] = target[(b0 + ln) * 3 + r];
    }
    float b3v[4];
#pragma unroll
    for (int r = 0; r < 4; ++r) {
        const int f = q * 4 + r;
        b3v[r] = (f < NSD) ? b3[f] : 0.0f;
    }
    float costAcc = 0.0f;

    STAGE(0, 0);                                      // prologue: slice 0
    asm volatile("s_waitcnt vmcnt(0)" ::: "memory");
    __syncthreads();   // b2L + initial inpL + staged slice 0
    int cur = 0;

    const floatx4 z4 = {0.0f, 0.0f, 0.0f, 0.0f};

    for (int h = 0; h < horizon; ++h) {
        // ---- inp B-frag: lane (q,ln) holds inp[ln][8q+j] (hi/lo) ----
        const float* row = &inpL[wv][ln][0];
        float4 fa = {0, 0, 0, 0}, fb = {0, 0, 0, 0};
        if (q < 3) fa = *(const float4*)&row[8 * q];
        if (q < 2) fb = *(const float4*)&row[8 * q + 4];
        half8 bh, bl;
        {
            const float vv[8] = {fa.x, fa.y, fa.z, fa.w, fb.x, fb.y, fb.z, fb.w};
#pragma unroll
            for (int j = 0; j < 8; ++j) {
                const _Float16 hh = (_Float16)vv[j];
                bh[j] = hh;
                bl[j] = (_Float16)((vv[j] - (float)hh) * LOSCALE);
            }
        }

        // ---- L2 accumulator banks (persistent across kc; AGPR) ----
        floatx4 C1[16], C2[16];
#pragma unroll
        for (int t = 0; t < 16; ++t) { C1[t] = z4; C2[t] = z4; }

        // ---- kc loop: stage next slice; L1 + t-loop all from LDS ----
        for (int kc = 0; kc < 8; ++kc) {
            const int nkc = (kc < 7) ? kc + 1 : 0;    // kc=7 restages slice 0
            STAGE(cur ^ 1, nkc);                      // for next kc / next h

            // L1 for this kc from sb[cur] p1 region (ds_read -> lgkmcnt only).
            half8 h1h, h1l;
            {
                const half8 a1h0 = *(const half8*)&sb[cur][16384 + lane*8];
                const half8 a1l0 = *(const half8*)&sb[cur][16384 + 512 + lane*8];
                const half8 a1h1 = *(const half8*)&sb[cur][16384 + 1024 + lane*8];
                const half8 a1l1 = *(const half8*)&sb[cur][16384 + 1536 + lane*8];
                floatx4 c1t = __builtin_amdgcn_mfma_f32_16x16x32_f16(a1h0, bh, z4, 0, 0, 0);
                floatx4 c2t = __builtin_amdgcn_mfma_f32_16x16x32_f16(a1h0, bl, z4, 0, 0, 0);
                c2t = __builtin_amdgcn_mfma_f32_16x16x32_f16(a1l0, bh, c2t, 0, 0, 0);
#pragma unroll
                for (int r = 0; r < 4; ++r) {
                    const float v = fmaxf(fmaf(c2t[r], LOINV, c1t[r]), 0.0f);
                    const _Float16 hh = (_Float16)v;
                    h1h[r] = hh;
                    h1l[r] = (_Float16)((v - (float)hh) * LOSCALE);
                }
                c1t = __builtin_amdgcn_mfma_f32_16x16x32_f16(a1h1, bh, z4, 0, 0, 0);
                c2t = __builtin_amdgcn_mfma_f32_16x16x32_f16(a1h1, bl, z4, 0, 0, 0);
                c2t = __builtin_amdgcn_mfma_f32_16x16x32_f16(a1l1, bh, c2t, 0, 0, 0);
#pragma unroll
                for (int r = 0; r < 4; ++r) {
                    const float v = fmaxf(fmaf(c2t[r], LOINV, c1t[r]), 0.0f);
                    const _Float16 hh = (_Float16)v;
                    h1h[4 + r] = hh;
                    h1l[4 + r] = (_Float16)((v - (float)hh) * LOSCALE);
                }
            }

            // t-loop: 16 t x 3 MFMA on sb[cur] w2 region.
#pragma unroll
            for (int t = 0; t < 16; ++t) {
                const half8 a2h = *(const half8*)&sb[cur][t * 1024 + lane * 8];
                const half8 a2l = *(const half8*)&sb[cur][t * 1024 + 512 + lane * 8];
                C1[t] = __builtin_amdgcn_mfma_f32_16x16x32_f16(a2h, h1h, C1[t], 0, 0, 0);
                C2[t] = __builtin_amdgcn_mfma_f32_16x16x32_f16(a2h, h1l, C2[t], 0, 0, 0);
                C2[t] = __builtin_amdgcn_mfma_f32_16x16x32_f16(a2l, h1h, C2[t], 0, 0, 0);
            }

            __syncthreads();   // implicit vmcnt(0): stage landed during L1+t-loop
            cur ^= 1;
        }

        // ---- epilogue: finish h2 per t, fuse L3 per completed k-slice ----
        floatx4 D1 = z4, D2 = z4;
        half8 h2h, h2l;
#pragma unroll
        for (int t = 0; t < 16; ++t) {
            const float4 bb = *(const float4*)&b2L[32*(t>>1) + 8*q + 4*(t&1)];
            const float bbv[4] = {bb.x, bb.y, bb.z, bb.w};
#pragma unroll
            for (int r = 0; r < 4; ++r) {
                const float v = fmaxf(C1[t][r] + LOINV * C2[t][r] + bbv[r], 0.0f);
                const _Float16 hh = (_Float16)v;
                h2h[(t & 1) * 4 + r] = hh;
                h2l[(t & 1) * 4 + r] = (_Float16)((v - (float)hh) * LOSCALE);
            }
            if (t & 1) {
                const int kc2 = t >> 1;
                const half8 a3h = *(const half8*)&p3[(size_t)kc2 * 1024 + lane*8];
                const half8 a3l = *(const half8*)&p3[(size_t)kc2 * 1024 + 512 + lane*8];
                D1 = __builtin_amdgcn_mfma_f32_16x16x32_f16(a3h, h2h, D1, 0, 0, 0);
                D2 = __builtin_amdgcn_mfma_f32_16x16x32_f16(a3h, h2l, D2, 0, 0, 0);
                D2 = __builtin_amdgcn_mfma_f32_16x16x32_f16(a3l, h2h, D2, 0, 0, 0);
            }
        }
        float v[4];
#pragma unroll
        for (int r = 0; r < 4; ++r)
            v[r] = D1[r] + LOINV * D2[r] + b3v[r];

        // lane (q,ln) holds sim'[ln][features 4q..4q+3]
        if (q == 0) {
            const float d0 = v[0] - tg[0], d1 = v[1] - tg[1], d2 = v[2] - tg[2];
            costAcc += d0 * d0 + d1 * d1 + d2 * d2;
        }
        if (q < 2) {
            const float4 w4 = {v[0], v[1], v[2], v[3]};
            *(float4*)&inpL[wv][ln][4 * q] = w4;
        } else if (q == 2) {
            inpL[wv][ln][8] = v[0];   // feature 8 only (9..11 would hit cand)
        }
        // order sim' writes before next iteration's cross-lane reads
        asm volatile("s_waitcnt lgkmcnt(0)" ::: "memory");
    }

    if (q == 0) cost[(size_t)s * B + b0 + ln] = costAcc;
}

// ---------------------------------------------------------------------------
// Kernel 3: first-argmin over samples + gather best action (unchanged).
// ---------------------------------------------------------------------------
__global__ __launch_bounds__(256) void k_select(
    const float* __restrict__ cost, const float* __restrict__ cand,
    float* __restrict__ out, int B, int S)
{
    const int b = blockIdx.x * 256 + threadIdx.x;
    if (b >= B) return;
    float best = cost[b];
    int bs = 0;
    for (int s = 1; s < S; ++s) {
        const float c = cost[(size_t)s * B + b];
        if (c < best) { best = c; bs = s; }
    }
#pragma unroll
    for (int j = 0; j < NAD; ++j)
        out[b * NAD + j] = cand[((size_t)bs * B + b) * NAD + j];
}

// ---------------------------------------------------------------------------
extern "C" void kernel_launch(void* const* d_in, const int* in_sizes, int n_in,
                              void* d_out, int out_size, void* d_ws, size_t ws_size,
                              hipStream_t stream)
{
    const float* state   = (const float*)d_in[0];
    const float* proprio = (const float*)d_in[1];
    const float* target  = (const float*)d_in[2];
    const float* noise   = (const float*)d_in[3];
    const float* pw1     = (const float*)d_in[4];
    const float* pb1     = (const float*)d_in[5];
    const float* pw2     = (const float*)d_in[6];
    const float* pb2     = (const float*)d_in[7];
    const float* w1      = (const float*)d_in[8];
    const float* b1      = (const float*)d_in[9];
    const float* w2      = (const float*)d_in[10];
    const float* b2      = (const float*)d_in[11];
    const float* w3      = (const float*)d_in[12];
    const float* b3      = (const float*)d_in[13];
    const int*   horizon = (const int*)d_in[14];

    const int B = in_sizes[0] / NSD;             // 8192
    const int S = in_sizes[3] / (B * NAD);       // 8

    float* cand = (float*)d_ws;                            // S*B*7 floats
    float* cost = cand + (size_t)S * B * NAD;              // S*B floats
    _Float16* pc = (_Float16*)(cost + (size_t)S * B);      // 8*18432 fp16 (288 KB)
    _Float16* p3 = pc + 8 * 18432;                         // 8*1024 fp16 (16 KB)
    float* out  = (float*)d_out;

    k_packW<<<dim3(152), dim3(64), 0, stream>>>(w1, b1, w2, w3, pc, p3);
    k_proposal<<<dim3((B + 3) / 4), dim3(256), 0, stream>>>(
        state, proprio, noise, pw1, pb1, pw2, pb2, cand, B);
    k_rollout<<<dim3((S * B) / 64), dim3(256), 0, stream>>>(
        state, target, cand, pc, p3, b2, b3, horizon, cost, B);
    k_select<<<dim3((B + 255) / 256), dim3(256), 0, stream>>>(
        cost, cand, out, B, S);
}